// Round 4
// baseline (127.234 us; speedup 1.0000x reference)
//
#include <hip/hip_runtime.h>
#include <math.h>

// Problem constants (fixed by the reference)
#define BD   128      // batch == hidden
#define ID   1024     // img dim
#define TD   1024     // txt dim
#define NE   32768    // edges
#define HD   128      // hidden

// ---------------------------------------------------------------------------
// K_A: H precompute. 256 blocks x 256 threads, 8 feature-rows per block.
//   HimgT[i,h] = sum_b img[b,i]*W1[h,b]       (+ b1[h] folded in)
//   HtxtT[t,h] = sum_b text[b,t]*W1[h,128+b]
// W1-side staged TRANSPOSED into LDS in two 64-b halves (stride 129 ->
// conflict-free); S-tile staged via float4. Inner loop per b: 1 ds_read_b32
// (conflict-free across h-lanes) + 1 ds_read_b128 (broadcast) + 4 FMA.
// ---------------------------------------------------------------------------
__global__ __launch_bounds__(256) void h_kernel(
    const float* __restrict__ img, const float* __restrict__ text,
    const float* __restrict__ W1, const float* __restrict__ b1,
    float* __restrict__ HimgT, float* __restrict__ HtxtT)
{
    __shared__ __align__(16) float Wl[64 * 129];  // 33 KB: Wl[b'*129+h]
    __shared__ __align__(16) float Sl[128 * 8];   // 4 KB:  Sl[b*8+il]
    const int blk = blockIdx.x, tid = threadIdx.x;
    const int side = blk >> 7;            // 0: img, 1: txt (128 blocks each)
    const int i0 = (blk & 127) * 8;
    const float* S = side ? text : img;
    float* Dst = side ? HtxtT : HimgT;
    const int soff = side * 128;

    // stage S tile: 128 rows x 8 floats = 256 float4, one per thread (coalesced)
    {
        int b = tid >> 1, q = tid & 1;
        ((float4*)Sl)[tid] = *(const float4*)(S + b * 1024 + i0 + q * 4);
    }

    const int h = tid & 127, iq = tid >> 7;
    float acc[4] = {0.f, 0.f, 0.f, 0.f};
    #pragma unroll
    for (int half = 0; half < 2; half++) {
        __syncthreads();   // Sl ready (1st) / Wl no longer read (2nd)
        for (int idx = tid; idx < 8192; idx += 256) {
            int hh = idx >> 6, bb = idx & 63;
            Wl[bb * 129 + hh] = W1[hh * 256 + soff + half * 64 + bb];
        }
        __syncthreads();
        #pragma unroll 8
        for (int bb = 0; bb < 64; bb++) {
            int b = half * 64 + bb;
            float w = Wl[bb * 129 + h];                        // conflict-free
            float4 s4 = *(const float4*)(Sl + b * 8 + iq * 4); // broadcast
            acc[0] += s4.x * w; acc[1] += s4.y * w;
            acc[2] += s4.z * w; acc[3] += s4.w * w;
        }
    }
    float bias = side ? 0.f : b1[h];      // fold b1 into img side
    #pragma unroll
    for (int r = 0; r < 4; r++)
        Dst[(i0 + iq * 4 + r) * 128 + h] = acc[r] + bias;   // coalesced
}

// ---------------------------------------------------------------------------
// K_B: a[e] = sigmoid(w2 . relu(HimgT[src]+HtxtT[tgt]) + b2)
// 2048 blocks x 256 thr = 8192 waves (8/SIMD), 4 edges per wave.
// ---------------------------------------------------------------------------
__global__ __launch_bounds__(256) void edge_kernel(
    const int* __restrict__ src, const int* __restrict__ tgt,
    const float* __restrict__ HimgT, const float* __restrict__ HtxtT,
    const float* __restrict__ w2, const float* __restrict__ b2,
    float* __restrict__ a_e)
{
    const int lane = threadIdx.x & 63;
    const int wgid = blockIdx.x * 4 + (threadIdx.x >> 6);   // 0..8191
    const float w2a = w2[lane], w2b = w2[lane + 64];
    const float b2v = b2[0];
    #pragma unroll
    for (int k = 0; k < 4; k++) {
        int e = wgid * 4 + k;
        int s0 = src[e], t0 = tgt[e];
        const float* Hi = HimgT + s0 * 128;
        const float* Ht = HtxtT + t0 * 128;
        float v1 = Hi[lane]      + Ht[lane];
        float v2 = Hi[lane + 64] + Ht[lane + 64];
        float x = fmaxf(v1, 0.f) * w2a + fmaxf(v2, 0.f) * w2b;
        #pragma unroll
        for (int off = 32; off > 0; off >>= 1)
            x += __shfl_xor(x, off, 64);
        if (lane == 0)
            a_e[e] = 1.f / (1.f + expf(-(x + b2v)));
    }
}

// ---------------------------------------------------------------------------
// K_C: batch-major scatter, 2048 blocks = (side, batch-row, edge-chunk/8).
//   attended_img[b,i]  = sum_{e:src=i} a[e]*text[b,tgt[e]]
//   attended_text[b,t] = sum_{e:tgt=t} a[e]*img[b,src[e]]
// 8 blocks/CU x 4 waves = full 32-wave occupancy to hide the L2-load ->
// LDS-atomic latency chain (R3's version had 1 block/CU and was latency-
// bound at 46 us). Each block: 4096 edges into private LDS acc, then
// global atomicAdd flush into pre-zeroed d_out (8-way contention).
// ---------------------------------------------------------------------------
__global__ __launch_bounds__(256) void scatter_kernel(
    const int* __restrict__ src, const int* __restrict__ tgt,
    const float* __restrict__ a_e,
    const float* __restrict__ img, const float* __restrict__ text,
    float* __restrict__ out)
{
    __shared__ float acc[1024];
    __shared__ float rowl[1024];
    const int blk = blockIdx.x, tid = threadIdx.x;
    const int side  = blk >> 10;           // 0: attended_img, 1: attended_text
    const int b     = (blk & 1023) >> 3;   // batch row 0..127
    const int chunk = blk & 7;             // edge chunk 0..7
    const float* Row = (side ? img : text) + b * 1024;
    #pragma unroll
    for (int k = 0; k < 4; k++) {
        int idx = k * 256 + tid;
        rowl[idx] = Row[idx];     // coalesced 4 KB stage
        acc[idx]  = 0.f;
    }
    __syncthreads();
    const int4*   s4 = (const int4*)src;
    const int4*   t4 = (const int4*)tgt;
    const float4* a4 = (const float4*)a_e;
    #pragma unroll
    for (int k = 0; k < 4; k++) {
        int idx = chunk * 1024 + k * 256 + tid;   // 4096 edges as int4
        int4 ss = s4[idx]; int4 tt = t4[idx]; float4 aa = a4[idx];
        if (side == 0) {
            atomicAdd(&acc[ss.x], aa.x * rowl[tt.x]);
            atomicAdd(&acc[ss.y], aa.y * rowl[tt.y]);
            atomicAdd(&acc[ss.z], aa.z * rowl[tt.z]);
            atomicAdd(&acc[ss.w], aa.w * rowl[tt.w]);
        } else {
            atomicAdd(&acc[tt.x], aa.x * rowl[ss.x]);
            atomicAdd(&acc[tt.y], aa.y * rowl[ss.y]);
            atomicAdd(&acc[tt.z], aa.z * rowl[ss.z]);
            atomicAdd(&acc[tt.w], aa.w * rowl[ss.w]);
        }
    }
    __syncthreads();
    float* obase = out + side * (BD * ID) + b * 1024;
    #pragma unroll
    for (int k = 0; k < 4; k++) {
        int idx = k * 256 + tid;
        atomicAdd(&obase[idx], acc[idx]);   // coalesced, 8-way contention
    }
}

extern "C" void kernel_launch(void* const* d_in, const int* in_sizes, int n_in,
                              void* d_out, int out_size, void* d_ws, size_t ws_size,
                              hipStream_t stream)
{
    const float* img  = (const float*)d_in[0];   // [128,1024]
    const float* text = (const float*)d_in[1];   // [128,1024]
    const int*   src  = (const int*)  d_in[2];   // [32768]
    const int*   tgt  = (const int*)  d_in[3];   // [32768]
    const float* W1   = (const float*)d_in[4];   // [128,256]
    const float* b1   = (const float*)d_in[5];   // [128]
    const float* w2   = (const float*)d_in[6];   // [128]
    const float* b2   = (const float*)d_in[7];   // [1]
    float* out = (float*)d_out;                  // 2 x [128,1024] concat

    // workspace: 1.18 MB
    float* HimgT = (float*)d_ws;         // 131072 floats (b1 folded in)
    float* HtxtT = HimgT + 131072;       // 131072
    float* a_e   = HtxtT + 131072;       // 32768

    hipMemsetAsync(out, 0, (size_t)out_size * sizeof(float), stream);
    h_kernel<<<256, 256, 0, stream>>>(img, text, W1, b1, HimgT, HtxtT);
    edge_kernel<<<2048, 256, 0, stream>>>(src, tgt, HimgT, HtxtT, w2, b2, a_e);
    scatter_kernel<<<2048, 256, 0, stream>>>(src, tgt, a_e, img, text, out);
}